// Round 3
// baseline (237.303 us; speedup 1.0000x reference)
//
#include <hip/hip_runtime.h>
#include <math.h>

// Batched expm of 4x4 fp32 matrices: out[m] = expm(A[m] * t[m / S]).
// Scaling-and-squaring identical in structure to the reference:
//   s = clip(ceil(log2(max(||Qt||_inf,1e-30)/0.5)), 0, 16)
//   As = Qt * 2^-s ; P = Taylor(As) ; P = P^(2^s)
// Taylor evaluated to degree 9 via Paterson-Stockmeyer (4 matmuls instead of 9
// sequential ones; truncation 0.5^10/10! ~ 2.7e-10 rel, below fp32 noise).
//
// Round-2 lesson: the kernel is STALL-bound, not bandwidth- or pattern-bound
// (coalesced LDS staging == strided direct access == ~80 us; memset hits
// 6.7 TB/s in the same trace). So: no LDS, no barriers, 2 matrices/thread
// with all 8 dwordx4 loads issued before any compute (latency hidden by ILP),
// and no per-thread integer division (t-index is block-uniform).

typedef float f4 __attribute__((ext_vector_type(4)));

constexpr int NMAT = 2;          // matrices per thread
constexpr int TPB  = 256;        // threads per block
constexpr int MPB  = NMAT * TPB; // matrices per block = 512

__device__ __forceinline__ void mm4(float* __restrict__ D,
                                    const float* __restrict__ X,
                                    const float* __restrict__ Y)
{
    #pragma unroll
    for (int i = 0; i < 4; ++i) {
        const float x0 = X[4*i+0], x1 = X[4*i+1];
        const float x2 = X[4*i+2], x3 = X[4*i+3];
        #pragma unroll
        for (int j = 0; j < 4; ++j) {
            float v = x0 * Y[j];
            v = __builtin_fmaf(x1, Y[4+j],  v);
            v = __builtin_fmaf(x2, Y[8+j],  v);
            v = __builtin_fmaf(x3, Y[12+j], v);
            D[4*i+j] = v;
        }
    }
}

// expm of one 4x4 given its raw rows r[4] and the (uniform) time t.
__device__ __forceinline__ void expm4_one(const f4 r[4], float t, f4 o[4])
{
    // ---- infinity norm of Qt = A*t, computed as (max abs row sum of A)*|t|
    //      directly off the load registers (shortens the serial prologue) ----
    const float at = fabsf(t);
    float nrm = 0.0f;
    #pragma unroll
    for (int i = 0; i < 4; ++i) {
        float rs = fabsf(r[i].x) + fabsf(r[i].y) + fabsf(r[i].z) + fabsf(r[i].w);
        nrm = fmaxf(nrm, rs);
    }
    nrm *= at;

    // ---- squaring count + combined scale ----
    float sf = ceilf(log2f(fmaxf(nrm, 1e-30f) * 2.0f));   // log2(nrm/0.5)
    sf = fminf(fmaxf(sf, 0.0f), 16.0f);
    const int   si = (int)sf;
    const float c  = t * exp2f(-sf);                       // t * 2^-s in one mul

    float a[16];
    #pragma unroll
    for (int i = 0; i < 4; ++i) {
        a[4*i+0] = r[i].x * c;
        a[4*i+1] = r[i].y * c;
        a[4*i+2] = r[i].z * c;
        a[4*i+3] = r[i].w * c;
    }

    // ---- powers ----
    float A2[16], A3[16];
    mm4(A2, a, a);     // As^2
    mm4(A3, A2, a);    // As^3

    // ---- Paterson-Stockmeyer groups ----
    constexpr float C2 = 1.0f/2.0f,     C3 = 1.0f/6.0f;
    constexpr float C4 = 1.0f/24.0f,    C5 = 1.0f/120.0f;
    constexpr float C6 = 1.0f/720.0f,   C7 = 1.0f/5040.0f;
    constexpr float C8 = 1.0f/40320.0f, C9 = 1.0f/362880.0f;

    float G[16], HI[16], PI[16];
    #pragma unroll
    for (int i = 0; i < 16; ++i) {
        G[i]  = __builtin_fmaf(C9, A3[i],
                __builtin_fmaf(C8, A2[i], C7 * a[i]));
        HI[i] = __builtin_fmaf(C5, A2[i], C4 * a[i]);
        PI[i] = __builtin_fmaf(C2, A2[i], a[i]);
    }
    G[0]  += C6; G[5]  += C6; G[10] += C6; G[15] += C6;
    HI[0] += C3; HI[5] += C3; HI[10] += C3; HI[15] += C3;
    PI[0] += 1.0f; PI[5] += 1.0f; PI[10] += 1.0f; PI[15] += 1.0f;
    // a, A2 now dead.

    // ---- H = G*A3 + HI ----
    float H[16];
    #pragma unroll
    for (int i = 0; i < 4; ++i) {
        const float g0 = G[4*i+0], g1 = G[4*i+1];
        const float g2 = G[4*i+2], g3 = G[4*i+3];
        #pragma unroll
        for (int j = 0; j < 4; ++j) {
            float v = HI[4*i+j];
            v = __builtin_fmaf(g0, A3[j],    v);
            v = __builtin_fmaf(g1, A3[4+j],  v);
            v = __builtin_fmaf(g2, A3[8+j],  v);
            v = __builtin_fmaf(g3, A3[12+j], v);
            H[4*i+j] = v;
        }
    }

    // ---- P = H*A3 + PI ----
    float P[16];
    #pragma unroll
    for (int i = 0; i < 4; ++i) {
        const float h0 = H[4*i+0], h1 = H[4*i+1];
        const float h2 = H[4*i+2], h3 = H[4*i+3];
        #pragma unroll
        for (int j = 0; j < 4; ++j) {
            float v = PI[4*i+j];
            v = __builtin_fmaf(h0, A3[j],    v);
            v = __builtin_fmaf(h1, A3[4+j],  v);
            v = __builtin_fmaf(h2, A3[8+j],  v);
            v = __builtin_fmaf(h3, A3[12+j], v);
            P[4*i+j] = v;
        }
    }

    // ---- undo scaling: square si times (2x-unrolled ping-pong; wave pays
    //      max si over its lanes) ----
    int it = si;
    while (it >= 2) {
        float Q[16];
        mm4(Q, P, P);
        mm4(P, Q, Q);
        it -= 2;
    }
    if (it) {
        float Q[16];
        mm4(Q, P, P);
        #pragma unroll
        for (int i = 0; i < 16; ++i) P[i] = Q[i];
    }

    #pragma unroll
    for (int i = 0; i < 4; ++i) {
        f4 v; v.x = P[4*i+0]; v.y = P[4*i+1]; v.z = P[4*i+2]; v.w = P[4*i+3];
        o[i] = v;
    }
}

__global__ void __launch_bounds__(TPB) expm4_kernel(
    const float* __restrict__ A,
    const float* __restrict__ tvec,
    float* __restrict__ out,
    int M, int S, int s_blocks)   // s_blocks = S/MPB if divisible, else 0
{
    const int tid = threadIdx.x;
    const long long mat0 = (long long)blockIdx.x * MPB;
    const long long m0 = mat0 + tid;          // first matrix of this thread
    const long long m1 = m0 + TPB;            // second matrix

    // ---- t: block-uniform when s_blocks > 0 (one scalar div per block) ----
    float t0, t1;
    if (s_blocks > 0) {
        const float t = tvec[blockIdx.x / s_blocks];
        t0 = t; t1 = t;
    } else {
        t0 = tvec[(int)(m0 / S)];
        t1 = (m1 < M) ? tvec[(int)(m1 / S)] : 0.0f;
    }

    // ---- issue all 8 dwordx4 loads before any compute ----
    const f4* Ap = reinterpret_cast<const f4*>(A);
    f4 r0[4], r1[4];
    const bool v0 = (m0 < M), v1 = (m1 < M);
    if (v0) {
        #pragma unroll
        for (int k = 0; k < 4; ++k) r0[k] = Ap[m0 * 4 + k];
    }
    if (v1) {
        #pragma unroll
        for (int k = 0; k < 4; ++k) r1[k] = Ap[m1 * 4 + k];
    }

    f4* Op = reinterpret_cast<f4*>(out);

    if (v0) {
        f4 o[4];
        expm4_one(r0, t0, o);
        #pragma unroll
        for (int k = 0; k < 4; ++k) Op[m0 * 4 + k] = o[k];
    }
    if (v1) {
        f4 o[4];
        expm4_one(r1, t1, o);
        #pragma unroll
        for (int k = 0; k < 4; ++k) Op[m1 * 4 + k] = o[k];
    }
}

extern "C" void kernel_launch(void* const* d_in, const int* in_sizes, int n_in,
                              void* d_out, int out_size, void* d_ws, size_t ws_size,
                              hipStream_t stream) {
    const float* A    = (const float*)d_in[0];   // [B, S, 4, 4] fp32
    const float* tvec = (const float*)d_in[1];   // [B] fp32
    float* out        = (float*)d_out;           // [B, S, 4, 4] fp32

    const int B = in_sizes[1];
    const int M = in_sizes[0] / 16;              // total 4x4 matrices
    const int S = M / B;                         // matrices per batch item

    // t is uniform across a block iff every block of MPB matrices sits inside
    // one batch item, i.e. MPB divides S.
    const int s_blocks = (S % MPB == 0) ? (S / MPB) : 0;

    const int blocks = (M + MPB - 1) / MPB;
    expm4_kernel<<<blocks, TPB, 0, stream>>>(A, tvec, out, M, S, s_blocks);
}